// Round 9
// baseline (476.984 us; speedup 1.0000x reference)
//
#include <hip/hip_runtime.h>

typedef float f32x4 __attribute__((ext_vector_type(4), aligned(4)));

// One pixel per thread, NO LDS, no inline-asm waits.
// Each lane reads its own 75 contiguous filts floats as 4 unaligned f32x4
// per tap-row (chunks at +0,+4,+8,+11 -> floats 0..14 used, float 11 dup).
// All touched lines are fully consumed (streaming read, L1 absorbs the
// chunk overlap). No LDS => __launch_bounds__(256,4) => 16 waves/CU —
// 2x the independent HBM streams of any staged variant.

__global__ __launch_bounds__(256, 4)
void convolve_kernel(const float* __restrict__ img,
                     const float* __restrict__ filts,
                     float* __restrict__ out)
{
    // bijective XCD-chunked swizzle (4096 % 8 == 0): XCD x gets a contiguous
    // 512-block chunk = 128K consecutive pixels (img slice ~1.6MB in its L2).
    const int bswz = ((int)blockIdx.x & 7) * 512 + ((int)blockIdx.x >> 3);
    const int p    = bswz * 256 + (int)threadIdx.x;

    const int b  = p >> 18;                 // / (512*512)
    const int hw = p & ((1 << 18) - 1);
    const int h  = hw >> 9;
    const int w  = hw & 511;

    const float* fp   = filts + (size_t)p * 75;
    const float* imgb = img + (size_t)b * (512u * 512u * 3u);
    const bool interior = (w >= 2) && (w <= 508);
    const float* q0 = imgb + (w - 2) * 3;

    float a0 = 0.f, a1 = 0.f, a2 = 0.f;

    #pragma unroll
    for (int di = 0; di < 5; ++di) {
        const int hh = h + di - 2;

        // ---- filts row chunk: floats di*15 .. di*15+14 (chunk3 at +11) ----
        const float* fr = fp + di * 15;
        const f32x4 f0 = __builtin_nontemporal_load((const f32x4*)(fr));
        const f32x4 f1 = __builtin_nontemporal_load((const f32x4*)(fr + 4));
        const f32x4 f2 = __builtin_nontemporal_load((const f32x4*)(fr + 8));
        const f32x4 f3 = __builtin_nontemporal_load((const f32x4*)(fr + 11));

        // ---- img row: 15 floats starting at (w-2)*3 (chunk3 at +11) ----
        f32x4 i0 = (f32x4)0.f, i1 = (f32x4)0.f, i2 = (f32x4)0.f, i3 = (f32x4)0.f;
        if ((unsigned)hh < 512u) {
            if (interior) {
                const float* q = q0 + (size_t)hh * 1536;
                i0 = *(const f32x4*)(q);
                i1 = *(const f32x4*)(q + 4);
                i2 = *(const f32x4*)(q + 8);
                i3 = *(const f32x4*)(q + 11);
            } else {
                const float* row = imgb + (size_t)hh * 1536;
                // guarded scalar fills, all indices compile-time static
                #pragma unroll
                for (int dj = 0; dj < 5; ++dj) {
                    const int ww = w + dj - 2;
                    if ((unsigned)ww < 512u) {
                        #pragma unroll
                        for (int c = 0; c < 3; ++c) {
                            const int idx = dj * 3 + c;     // 0..14, constant
                            const float val = row[ww * 3 + c];
                            if      (idx < 4)   i0[idx]      = val;
                            else if (idx < 8)   i1[idx - 4]  = val;
                            else if (idx < 12)  i2[idx - 8]  = val;
                            if      (idx >= 11) i3[idx - 11] = val; // 11 dup ok
                        }
                    }
                }
            }
        }

        // ---- 15 FMAs (float 15 excluded; chunk3 uses lanes y,z,w) ----
        a0 += i0.x * f0.x;  a1 += i0.y * f0.y;  a2 += i0.z * f0.z;
        a0 += i0.w * f0.w;  a1 += i1.x * f1.x;  a2 += i1.y * f1.y;
        a0 += i1.z * f1.z;  a1 += i1.w * f1.w;  a2 += i2.x * f2.x;
        a0 += i2.y * f2.y;  a1 += i2.z * f2.z;  a2 += i2.w * f2.w;
        a0 += i3.y * f3.y;  a1 += i3.z * f3.z;  a2 += i3.w * f3.w;
    }

    out[p] = a0 + a1 + a2;
}

extern "C" void kernel_launch(void* const* d_in, const int* in_sizes, int n_in,
                              void* d_out, int out_size, void* d_ws, size_t ws_size,
                              hipStream_t stream)
{
    const float* img   = (const float*)d_in[0];   // [4,512,512,3]  f32
    const float* filts = (const float*)d_in[1];   // [4,512,512,75] f32
    float* out         = (float*)d_out;           // [4,512,512]    f32

    // 1,048,576 pixels / 256 per block = 4096 blocks
    convolve_kernel<<<4096, 256, 0, stream>>>(img, filts, out);
}

// Round 10
// 237.397 us; speedup vs baseline: 2.0092x; 2.0092x over previous
//
#include <hip/hip_runtime.h>

typedef float f32x4 __attribute__((ext_vector_type(4), aligned(4)));

// One pixel per thread, NO LDS, no inline-asm waits, no cache-bypass hints.
// Each lane reads its own 75 contiguous filts floats as 4 f32x4 per tap-row
// (chunks at +0,+4,+8,+11 -> floats 0..14 used, float 11 dup). Lines are
// L1-cached: each 64B line is HBM-fetched once, overlapping chunk reads hit
// L1. No LDS => 16 waves/CU — 2-4x the concurrency of any staged variant.
// R10 = R9 minus nontemporal (which forced ~3.5x HBM refetch).

__global__ __launch_bounds__(256, 4)
void convolve_kernel(const float* __restrict__ img,
                     const float* __restrict__ filts,
                     float* __restrict__ out)
{
    // bijective XCD-chunked swizzle (4096 % 8 == 0)
    const int bswz = ((int)blockIdx.x & 7) * 512 + ((int)blockIdx.x >> 3);
    const int p    = bswz * 256 + (int)threadIdx.x;

    const int b  = p >> 18;                 // / (512*512)
    const int hw = p & ((1 << 18) - 1);
    const int h  = hw >> 9;
    const int w  = hw & 511;

    const float* fp   = filts + (size_t)p * 75;
    const float* imgb = img + (size_t)b * (512u * 512u * 3u);
    const bool interior = (w >= 2) && (w <= 508);
    const float* q0 = imgb + (w - 2) * 3;

    float a0 = 0.f, a1 = 0.f, a2 = 0.f;

    #pragma unroll
    for (int di = 0; di < 5; ++di) {
        const int hh = h + di - 2;

        // ---- filts row chunk: floats di*15 .. di*15+14 (chunk3 at +11) ----
        const float* fr = fp + di * 15;
        const f32x4 f0 = *(const f32x4*)(fr);
        const f32x4 f1 = *(const f32x4*)(fr + 4);
        const f32x4 f2 = *(const f32x4*)(fr + 8);
        const f32x4 f3 = *(const f32x4*)(fr + 11);

        // ---- img row: 15 floats starting at (w-2)*3 (chunk3 at +11) ----
        f32x4 i0 = (f32x4)0.f, i1 = (f32x4)0.f, i2 = (f32x4)0.f, i3 = (f32x4)0.f;
        if ((unsigned)hh < 512u) {
            if (interior) {
                const float* q = q0 + (size_t)hh * 1536;
                i0 = *(const f32x4*)(q);
                i1 = *(const f32x4*)(q + 4);
                i2 = *(const f32x4*)(q + 8);
                i3 = *(const f32x4*)(q + 11);
            } else {
                const float* row = imgb + (size_t)hh * 1536;
                // guarded scalar fills, all indices compile-time static
                #pragma unroll
                for (int dj = 0; dj < 5; ++dj) {
                    const int ww = w + dj - 2;
                    if ((unsigned)ww < 512u) {
                        #pragma unroll
                        for (int c = 0; c < 3; ++c) {
                            const int idx = dj * 3 + c;     // 0..14, constant
                            const float val = row[ww * 3 + c];
                            if      (idx < 4)   i0[idx]      = val;
                            else if (idx < 8)   i1[idx - 4]  = val;
                            else if (idx < 12)  i2[idx - 8]  = val;
                            if      (idx >= 11) i3[idx - 11] = val; // 11 dup ok
                        }
                    }
                }
            }
        }

        // ---- 15 FMAs (chunk3 uses lanes y,z,w) ----
        a0 += i0.x * f0.x;  a1 += i0.y * f0.y;  a2 += i0.z * f0.z;
        a0 += i0.w * f0.w;  a1 += i1.x * f1.x;  a2 += i1.y * f1.y;
        a0 += i1.z * f1.z;  a1 += i1.w * f1.w;  a2 += i2.x * f2.x;
        a0 += i2.y * f2.y;  a1 += i2.z * f2.z;  a2 += i2.w * f2.w;
        a0 += i3.y * f3.y;  a1 += i3.z * f3.z;  a2 += i3.w * f3.w;
    }

    out[p] = a0 + a1 + a2;
}

extern "C" void kernel_launch(void* const* d_in, const int* in_sizes, int n_in,
                              void* d_out, int out_size, void* d_ws, size_t ws_size,
                              hipStream_t stream)
{
    const float* img   = (const float*)d_in[0];   // [4,512,512,3]  f32
    const float* filts = (const float*)d_in[1];   // [4,512,512,75] f32
    float* out         = (float*)d_out;           // [4,512,512]    f32

    // 1,048,576 pixels / 256 per block = 4096 blocks
    convolve_kernel<<<4096, 256, 0, stream>>>(img, filts, out);
}

// Round 11
// 68.303 us; speedup vs baseline: 6.9834x; 3.4757x over previous
//
#include <hip/hip_runtime.h>

#define FC  75                 // K*K*C floats per pixel
#define GP  64                 // pixels per block = lanes per wave
#define SLABF 4864             // 1216 float4: 1200 data + 16 pad for clamp tail

typedef float f32x4 __attribute__((ext_vector_type(4), aligned(4)));

// R6 structure (best: 79.5 us), single change: stage loads carry the NT
// cache-policy bit (aux=2) -> non-temporal read, no L2/L3 allocation.
// filts is 315 MB read-once (> 256 MB L3): allocating it evicts useful
// lines and may throttle the read stream. Staged reads touch each line
// exactly once, so NT cannot increase FETCH_SIZE (unlike R9's per-lane nt).
// img loads stay cached (they have 25x reuse).

__global__ __launch_bounds__(64, 2)
void convolve_kernel(const float* __restrict__ img,
                     const float* __restrict__ filts,
                     float* __restrict__ out)
{
    __shared__ float slab[SLABF];

    const int lane = threadIdx.x;          // 0..63

    // bijective XCD-chunked swizzle (16384 % 8 == 0): XCD x gets groups
    // [x*2048, (x+1)*2048) = 128K consecutive pixels -> ~1.6MB img slice in L2.
    const int g = ((int)blockIdx.x & 7) * 2048 + ((int)blockIdx.x >> 3);

    // ---- stage this group's 4800 filts floats (1200 float4) into LDS ----
    {
        const f32x4* src4 = (const f32x4*)(filts + (size_t)g * (GP * FC));
        #pragma unroll
        for (int j = 0; j < 19; ++j) {
            int idx4 = j * 64 + lane;
            idx4 = idx4 > 1199 ? 1199 : idx4;   // clamp tail (writes land in pad)
            __builtin_amdgcn_global_load_lds(
                (const __attribute__((address_space(1))) void*)(src4 + idx4),
                (__attribute__((address_space(3))) void*)(slab + j * 256),
                16, 0, /*aux=NT*/ 2);
        }
    }
    asm volatile("s_waitcnt vmcnt(0)" ::: "memory");
    __builtin_amdgcn_sched_barrier(0);      // rule #18: ds_reads stay below wait

    // ---- compute: one pixel per lane ----
    const int p  = g * GP + lane;           // 64 consecutive pixels, same row
    const int b  = p >> 18;                 // / (512*512)
    const int hw = p & ((1 << 18) - 1);
    const int h  = hw >> 9;
    const int w  = hw & 511;

    const float* fp   = slab + lane * FC;   // stride 75 dwords -> 2/bank, free
    const float* imgb = img + (size_t)b * (512u * 512u * 3u);

    float a0 = 0.f, a1 = 0.f, a2 = 0.f;     // 3 chains vs FMA dep latency
    #pragma unroll
    for (int di = 0; di < 5; ++di) {
        const int hh = h + di - 2;
        if ((unsigned)hh < 512u) {           // wave-uniform (h uniform per group)
            const float* row = imgb + (size_t)hh * (512 * 3);
            #pragma unroll
            for (int dj = 0; dj < 5; ++dj) {
                const int ww = w + dj - 2;
                if ((unsigned)ww < 512u) {
                    const float* px = row + ww * 3;
                    const int fo = (di * 5 + dj) * 3;
                    a0 += px[0] * fp[fo + 0];
                    a1 += px[1] * fp[fo + 1];
                    a2 += px[2] * fp[fo + 2];
                }
            }
        }
    }
    out[p] = a0 + a1 + a2;
}

extern "C" void kernel_launch(void* const* d_in, const int* in_sizes, int n_in,
                              void* d_out, int out_size, void* d_ws, size_t ws_size,
                              hipStream_t stream)
{
    const float* img   = (const float*)d_in[0];   // [4,512,512,3]  f32
    const float* filts = (const float*)d_in[1];   // [4,512,512,75] f32
    float* out         = (float*)d_out;           // [4,512,512]    f32

    // 1,048,576 pixels / 64 per block = 16384 blocks of 64 threads
    convolve_kernel<<<16384, 64, 0, stream>>>(img, filts, out);
}